// Round 16
// baseline (168.345 us; speedup 1.0000x reference)
//
#include <hip/hip_runtime.h>

// GCN aggregation — single-pass dual partition + fused odeg/cast +
// fused (LDS-sort + full-row gather) aggregate, bf16 prescaled table.
//   out = diag(in_deg^-1/2) * A * diag(out_deg^-1/2) * concat(u_f, v_f)
//
// EXACT Round-13 configuration (last fully-validated pass: 166.4us,
// post-timing check OK). R14/R15's prep tweaks (relative cursors, CH=8192
// with 82KB LDS) REVERTED: R15 showed intermittent post-timing divergence.
//
// Pipeline (5 dispatches + 1 memset):
//   init  : gcurD[b]=gcurS[b]=b*BCAP
//   Pboth : ONE pass over (src,dst): dst-bucketed packed pairs -> partD,
//           src-key partition -> partS. Dual LDS histograms; dual scans
//           on waves 0-3 / 4-7; stage+flush pairs, then keys. (63.5KB LDS)
//   ocast : block per src-bucket: LDS histogram of partS window (= odeg),
//           then cast: tbl[node][128] = bf16(node_f * rsqrt(max(odeg,1)))
//   agg   : block per dst-bucket (512 thr): LDS counting-sort, then
//           wave-per-node full-row gather (quarter-wave pairing,
//           uint4/lane, k+=8 unroll), shfl_xor reduce, fused in-norm.
//
// Fallback (small ws): round-5 slack-CSR random-atomic build + f32 gather.

#define DFEAT 128
#define SLACK 64            // fallback only
#define OVF2_CAP 65536      // fallback only
#define OVFD_CAP 16384
#define BSHIFT 7
#define BNODES 128
#define MAXBUK 1024         // supports nN <= 131072
#define BCAP 2560           // mean 2048, sd~45 -> 11 sigma slack
#define CH 5888             // edges per partition chunk (63.5KB LDS total)

// ---------------- init ----------------
__global__ void init_kernel(int* __restrict__ gcurD, int* __restrict__ gcurS,
                            int nbuk) {
    int b = blockIdx.x * blockDim.x + threadIdx.x;
    if (b < nbuk) { gcurD[b] = b * BCAP; gcurS[b] = b * BCAP; }
}

// ---------------- single-pass dual partition ----------------
__global__ __launch_bounds__(512)
void partition_both_kernel(const int* __restrict__ src,
                           const int* __restrict__ dst,
                           int* __restrict__ gcurD,
                           int* __restrict__ gcurS,
                           unsigned* __restrict__ partD,   // packed dl<<24|src
                           unsigned* __restrict__ partS,   // src node id
                           int2* __restrict__ ovfD,
                           int* __restrict__ ovfD_cnt,
                           int* __restrict__ odeg_sp,      // key spills
                           int nE, int nbuk) {
    __shared__ int histD[MAXBUK], dltD[MAXBUK];
    __shared__ int histS[MAXBUK], dltS[MAXBUK];
    __shared__ int wsum[8];
    __shared__ unsigned sk[CH], sv[CH];

    int tid = threadIdx.x;
    long base = (long)blockIdx.x * CH;
    int n = (int)(((long)nE - base) < CH ? ((long)nE - base) : CH);
    if (n <= 0) return;

    for (int b = tid; b < nbuk; b += 512) { histD[b] = 0; histS[b] = 0; }
    __syncthreads();

    // both histograms in one read pass
    for (int i = tid; i < n; i += 512) {
        atomicAdd(&histD[((unsigned)dst[base + i]) >> BSHIFT], 1);
        atomicAdd(&histS[((unsigned)src[base + i]) >> BSHIFT], 1);
    }
    __syncthreads();

    // dual exclusive scan: waves 0-3 handle D, waves 4-7 handle S
    {
        int lane = tid & 63, wid = tid >> 6;
        bool isS = (wid >= 4);
        int* hist = isS ? histS : histD;
        int* dlt  = isS ? dltS  : dltD;
        int* gcur = isS ? gcurS : gcurD;
        int b0 = (isS ? (tid - 256) : tid) * 4;

        int c0 = 0, c1 = 0, c2 = 0, c3 = 0, sum = 0;
        if (b0 < nbuk) {
            c0 = hist[b0];
            c1 = (b0 + 1 < nbuk) ? hist[b0 + 1] : 0;
            c2 = (b0 + 2 < nbuk) ? hist[b0 + 2] : 0;
            c3 = (b0 + 3 < nbuk) ? hist[b0 + 3] : 0;
            sum = c0 + c1 + c2 + c3;
        }
        int x = sum;
        #pragma unroll
        for (int off = 1; off < 64; off <<= 1) {
            int t = __shfl_up(x, off, 64);
            if (lane >= off) x += t;
        }
        if (lane == 63) wsum[wid] = x;
        __syncthreads();
        int wpre = 0;
        for (int w = (isS ? 4 : 0); w < wid; ++w) wpre += wsum[w];
        int excl = wpre + x - sum;
        if (b0 < nbuk) {
            int lb = excl;
            hist[b0] = lb;
            if (c0) { int g = atomicAdd(&gcur[b0], c0); dlt[b0] = g - lb; }
            lb += c0;
            if (b0 + 1 < nbuk) {
                hist[b0 + 1] = lb;
                if (c1) { int g = atomicAdd(&gcur[b0 + 1], c1); dlt[b0 + 1] = g - lb; }
                lb += c1;
            }
            if (b0 + 2 < nbuk) {
                hist[b0 + 2] = lb;
                if (c2) { int g = atomicAdd(&gcur[b0 + 2], c2); dlt[b0 + 2] = g - lb; }
                lb += c2;
            }
            if (b0 + 3 < nbuk) {
                hist[b0 + 3] = lb;
                if (c3) { int g = atomicAdd(&gcur[b0 + 3], c3); dlt[b0 + 3] = g - lb; }
            }
        }
    }
    __syncthreads();

    // pairs: stage bucket-sorted, flush coalesced
    for (int i = tid; i < n; i += 512) {
        unsigned d = (unsigned)dst[base + i];
        unsigned s = (unsigned)src[base + i];
        int slot = atomicAdd(&histD[d >> BSHIFT], 1);
        sk[slot] = d; sv[slot] = s;
    }
    __syncthreads();
    for (int i = tid; i < n; i += 512) {
        unsigned d = sk[i], s = sv[i];
        int b = (int)(d >> BSHIFT);
        long dest = (long)dltD[b] + i;
        if (dest < (long)(b + 1) * BCAP) {
            partD[dest] = ((d & (BNODES - 1)) << 24) | s;
        } else {
            int q = atomicAdd(ovfD_cnt, 1);
            if (q < OVFD_CAP) ovfD[q] = make_int2((int)d, (int)s);
        }
    }
    __syncthreads();

    // keys: reuse sk stage
    for (int i = tid; i < n; i += 512) {
        unsigned s = (unsigned)src[base + i];
        int slot = atomicAdd(&histS[s >> BSHIFT], 1);
        sk[slot] = s;
    }
    __syncthreads();
    for (int i = tid; i < n; i += 512) {
        unsigned k = sk[i];
        int b = (int)(k >> BSHIFT);
        long dest = (long)dltS[b] + i;
        if (dest < (long)(b + 1) * BCAP) partS[dest] = k;
        else atomicAdd(&odeg_sp[k], 1);
    }
}

// ---------------- bf16 helpers ----------------
__device__ __forceinline__ unsigned short f2bf(float x) {
    unsigned u = __float_as_uint(x);
    u += 0x7fffu + ((u >> 16) & 1u);   // round-to-nearest-even
    return (unsigned short)(u >> 16);
}
__device__ __forceinline__ float bflo(unsigned u) { return __uint_as_float(u << 16); }
__device__ __forceinline__ float bfhi(unsigned u) { return __uint_as_float(u & 0xffff0000u); }

// ---------------- fused odeg histogram + cast ----------------
__global__ __launch_bounds__(256)
void odeg_cast_kernel(const unsigned* __restrict__ partS,
                      const int* __restrict__ gcurS,
                      const int* __restrict__ odeg_sp,
                      const float* __restrict__ u_f,
                      const float* __restrict__ v_f,
                      unsigned short* __restrict__ tbl,
                      int nN, int nU) {
    __shared__ int bins[BNODES];
    __shared__ float norms[BNODES];
    int tid = threadIdx.x;
    int bucket = blockIdx.x;
    int nodeBase = bucket << BSHIFT;

    if (tid < BNODES) bins[tid] = 0;
    __syncthreads();

    int start = bucket * BCAP;
    int endv  = gcurS[bucket];
    if (endv > start + BCAP) endv = start + BCAP;
    for (int i = start + tid; i < endv; i += 256)
        atomicAdd(&bins[(int)partS[i] - nodeBase], 1);
    __syncthreads();

    if (tid < BNODES) {
        int node = nodeBase + tid;
        int d = (node < nN) ? (bins[tid] + odeg_sp[node]) : 1;
        norms[tid] = rsqrtf((float)max(d, 1));
    }
    __syncthreads();

    for (int idx = tid; idx < BNODES * 32; idx += 256) {
        int nl = idx >> 5, q = idx & 31;
        int node = nodeBase + nl;
        if (node >= nN) continue;
        float norm = norms[nl];
        const float* basep = (node < nU) ? (u_f + (size_t)node * DFEAT)
                                         : (v_f + (size_t)(node - nU) * DFEAT);
        float4 v = ((const float4*)basep)[q];
        ushort4 o;
        o.x = f2bf(v.x * norm);
        o.y = f2bf(v.y * norm);
        o.z = f2bf(v.z * norm);
        o.w = f2bf(v.w * norm);
        ((ushort4*)tbl)[(size_t)node * 32 + q] = o;
    }
}

// ---------------- aggregate: fused LDS sort + full-row gather ----------------
__global__ __launch_bounds__(512)
void agg_fused_kernel(const unsigned short* __restrict__ tbl,
                      const unsigned* __restrict__ part,
                      const int* __restrict__ gcur,
                      const int2* __restrict__ ovfD,
                      const int* __restrict__ ovfD_cnt,
                      float* __restrict__ out,
                      int nN) {
    __shared__ unsigned sl[BCAP];
    __shared__ int bins[BNODES];    // counts -> begin offsets
    __shared__ int curs[BNODES];    // running cursor -> end offsets
    __shared__ int w0tot_s;

    int tid = threadIdx.x;
    int bucket = blockIdx.x;
    int nodeBase = bucket << BSHIFT;
    int lane = tid & 63;
    int wv   = tid >> 6;           // 0..7

    if (tid < BNODES) bins[tid] = 0;
    __syncthreads();

    int start = bucket * BCAP;
    int n = gcur[bucket] - start; if (n > BCAP) n = BCAP; if (n < 0) n = 0;

    for (int i = tid; i < n; i += 512)
        atomicAdd(&bins[part[start + i] >> 24], 1);
    __syncthreads();

    int v = 0, x = 0;
    if (tid < BNODES) {
        v = bins[tid];
        x = v;
        #pragma unroll
        for (int off = 1; off < 64; off <<= 1) {
            int t = __shfl_up(x, off, 64);
            if (lane >= off) x += t;
        }
        if (tid == 63) w0tot_s = x;
    }
    __syncthreads();
    if (tid < BNODES) {
        int excl = x - v + ((tid >= 64) ? w0tot_s : 0);
        bins[tid] = excl;
        curs[tid] = excl;
    }
    __syncthreads();

    for (int i = tid; i < n; i += 512) {
        unsigned p = part[start + i];
        int dl = (int)(p >> 24);
        int pos = atomicAdd(&curs[dl], 1);
        sl[pos] = p & 0xFFFFFFu;
    }
    __syncthreads();

    int q = lane >> 4;
    int l16 = lane & 15;
    const uint4* t = (const uint4*)tbl;   // 16 uint4 per 256B row
    int m = *ovfD_cnt;                    // 0 in practice
    if (m > OVFD_CAP) m = OVFD_CAP;

    for (int nl = wv; nl < BNODES; nl += 8) {
        int node = nodeBase + nl;
        if (node >= nN) continue;
        int beg  = bins[nl];
        int endn = curs[nl];
        int deg  = endn - beg;

        float a0 = 0.f, a1 = 0.f, a2 = 0.f, a3 = 0.f;
        float a4 = 0.f, a5 = 0.f, a6 = 0.f, a7 = 0.f;

        int k = beg;
        for (; k + 8 <= endn; k += 8) {
            unsigned s0 = sl[k + q];
            unsigned s1 = sl[k + 4 + q];
            uint4 w0 = t[(size_t)s0 * 16 + l16];
            uint4 w1 = t[(size_t)s1 * 16 + l16];
            a0 += bflo(w0.x); a1 += bfhi(w0.x);
            a2 += bflo(w0.y); a3 += bfhi(w0.y);
            a4 += bflo(w0.z); a5 += bfhi(w0.z);
            a6 += bflo(w0.w); a7 += bfhi(w0.w);
            a0 += bflo(w1.x); a1 += bfhi(w1.x);
            a2 += bflo(w1.y); a3 += bfhi(w1.y);
            a4 += bflo(w1.z); a5 += bfhi(w1.z);
            a6 += bflo(w1.w); a7 += bfhi(w1.w);
        }
        if (k + 4 <= endn) {
            unsigned s0 = sl[k + q];
            uint4 w0 = t[(size_t)s0 * 16 + l16];
            a0 += bflo(w0.x); a1 += bfhi(w0.x);
            a2 += bflo(w0.y); a3 += bfhi(w0.y);
            a4 += bflo(w0.z); a5 += bfhi(w0.z);
            a6 += bflo(w0.w); a7 += bfhi(w0.w);
            k += 4;
        }
        int r = endn - k;                 // 0..3
        if (q < r) {
            unsigned s0 = sl[k + q];
            uint4 w0 = t[(size_t)s0 * 16 + l16];
            a0 += bflo(w0.x); a1 += bfhi(w0.x);
            a2 += bflo(w0.y); a3 += bfhi(w0.y);
            a4 += bflo(w0.z); a5 += bfhi(w0.z);
            a6 += bflo(w0.w); a7 += bfhi(w0.w);
        }

        int extra = 0;
        if (m > 0) {                      // rare partition spill
            for (int j = q; j < m; j += 4) {
                int2 e = ovfD[j];
                if (e.x == node) {
                    uint4 w = t[(size_t)e.y * 16 + l16];
                    a0 += bflo(w.x); a1 += bfhi(w.x);
                    a2 += bflo(w.y); a3 += bfhi(w.y);
                    a4 += bflo(w.z); a5 += bfhi(w.z);
                    a6 += bflo(w.w); a7 += bfhi(w.w);
                    ++extra;
                }
            }
        }

        a0 += __shfl_xor(a0, 16, 64); a1 += __shfl_xor(a1, 16, 64);
        a2 += __shfl_xor(a2, 16, 64); a3 += __shfl_xor(a3, 16, 64);
        a4 += __shfl_xor(a4, 16, 64); a5 += __shfl_xor(a5, 16, 64);
        a6 += __shfl_xor(a6, 16, 64); a7 += __shfl_xor(a7, 16, 64);
        a0 += __shfl_xor(a0, 32, 64); a1 += __shfl_xor(a1, 32, 64);
        a2 += __shfl_xor(a2, 32, 64); a3 += __shfl_xor(a3, 32, 64);
        a4 += __shfl_xor(a4, 32, 64); a5 += __shfl_xor(a5, 32, 64);
        a6 += __shfl_xor(a6, 32, 64); a7 += __shfl_xor(a7, 32, 64);
        if (m > 0) {
            extra += __shfl_xor(extra, 16, 64);
            extra += __shfl_xor(extra, 32, 64);
        }

        if (lane < 16) {
            float inorm = rsqrtf((float)max(deg + extra, 1));
            float* orow = out + (size_t)node * DFEAT + l16 * 8;
            ((float4*)orow)[0] = make_float4(a0 * inorm, a1 * inorm,
                                             a2 * inorm, a3 * inorm);
            ((float4*)orow)[1] = make_float4(a4 * inorm, a5 * inorm,
                                             a6 * inorm, a7 * inorm);
        }
    }
}

// ---------------- fallback: round-5 random-atomic build ----------------
__global__ void build_kernel(const int* __restrict__ src,
                             const int* __restrict__ dst,
                             int* __restrict__ ideg,
                             int* __restrict__ odeg,
                             int* __restrict__ slack,
                             int2* __restrict__ ovf2,
                             int* __restrict__ ovf2_cnt,
                             int nE) {
    int t = blockIdx.x * blockDim.x + threadIdx.x;
    long base = (long)t * 4;
    if (base >= nE) return;
    long lim = base + 4 < (long)nE ? base + 4 : (long)nE;
    for (long e = base; e < lim; ++e) {
        int s = src[e], d = dst[e];
        atomicAdd(&odeg[s], 1);
        int p = atomicAdd(&ideg[d], 1);
        if (p < SLACK) {
            slack[(size_t)d * SLACK + p] = s;
        } else {
            int q = atomicAdd(ovf2_cnt, 1);
            if (q < OVF2_CAP) ovf2[q] = make_int2(d, s);
        }
    }
}

__launch_bounds__(256)
__global__ void aggregate_f32_kernel(const float* __restrict__ u_f,
                                     const float* __restrict__ v_f,
                                     const int* __restrict__ slack,
                                     const int* __restrict__ ideg,
                                     const int* __restrict__ odeg,
                                     const int2* __restrict__ ovf2,
                                     const int* __restrict__ ovf2_cnt,
                                     float* __restrict__ out,
                                     int nN, int nU) {
    int lane = threadIdx.x & 63;
    int wid  = threadIdx.x >> 6;
    int node = blockIdx.x * 4 + wid;
    if (node >= nN) return;

    int deg = ideg[node];
    int cnt = min(deg, SLACK);
    int   sb = 0;
    float nb = 0.f;
    if (lane < cnt) {
        sb = slack[(size_t)node * SLACK + lane];
        nb = rsqrtf((float)max(odeg[sb], 1));
    }
    float2 acc = make_float2(0.f, 0.f);
    for (int k = 0; k < cnt; ++k) {
        int   sk = __shfl(sb, k, 64);
        float nk = __shfl(nb, k, 64);
        const float* row = (sk < nU) ? (u_f + (size_t)sk * DFEAT)
                                     : (v_f + (size_t)(sk - nU) * DFEAT);
        float2 v = ((const float2*)row)[lane];
        acc.x += v.x * nk;
        acc.y += v.y * nk;
    }
    if (deg > SLACK) {
        int m = *ovf2_cnt; if (m > OVF2_CAP) m = OVF2_CAP;
        for (int j = 0; j < m; ++j) {
            int2 os = ovf2[j];
            if (os.x == node) {
                int sk = os.y;
                float nk = rsqrtf((float)max(odeg[sk], 1));
                const float* row = (sk < nU) ? (u_f + (size_t)sk * DFEAT)
                                             : (v_f + (size_t)(sk - nU) * DFEAT);
                float2 v = ((const float2*)row)[lane];
                acc.x += v.x * nk;
                acc.y += v.y * nk;
            }
        }
    }
    float inorm = rsqrtf((float)max(deg, 1));
    acc.x *= inorm; acc.y *= inorm;
    ((float2*)(out + (size_t)node * DFEAT))[lane] = acc;
}

extern "C" void kernel_launch(void* const* d_in, const int* in_sizes, int n_in,
                              void* d_out, int out_size, void* d_ws, size_t ws_size,
                              hipStream_t stream) {
    const float* u_f = (const float*)d_in[0];
    const float* v_f = (const float*)d_in[1];
    const int*   src = (const int*)d_in[2];
    const int*   dst = (const int*)d_in[3];
    float* out = (float*)d_out;

    int nU = in_sizes[0] / DFEAT;
    int nV = in_sizes[1] / DFEAT;
    int nN = nU + nV;
    int nE = in_sizes[2];
    int nbuk = (nN + BNODES - 1) >> BSHIFT;

    // ---- new-path workspace layout (ints) ----
    // odeg_sp | cnts | ovfD | gcurD | gcurS | partD | partS | tbl
    int*  odeg_sp = (int*)d_ws;              // nN
    int*  cnts    = odeg_sp + nN;            // 8; [1] = ovfD_cnt
    int2* ovfD    = (int2*)(cnts + 8);
    int*  gcurD   = (int*)(ovfD + OVFD_CAP);
    int*  gcurS   = gcurD + MAXBUK;
    unsigned* partD = (unsigned*)(gcurS + MAXBUK);
    unsigned* partS = partD + (size_t)nbuk * BCAP;
    unsigned short* tbl = (unsigned short*)(partS + (size_t)nbuk * BCAP);
    size_t needNew = ((size_t)nN + 8 + 2 * (size_t)OVFD_CAP + 2 * MAXBUK
                      + 2 * (size_t)nbuk * BCAP + (size_t)nN * (DFEAT / 2)) * 4;
    bool use_new = (nN <= (MAXBUK << BSHIFT)) && (nN < (1 << 24))
                   && (ws_size >= needNew);

    if (use_new) {
        hipMemsetAsync(d_ws, 0, ((size_t)nN + 8) * sizeof(int), stream);
        int nCh = (nE + CH - 1) / CH;
        init_kernel<<<(nbuk + 255) / 256, 256, 0, stream>>>(gcurD, gcurS, nbuk);
        partition_both_kernel<<<nCh, 512, 0, stream>>>(src, dst, gcurD, gcurS,
                                                       partD, partS, ovfD,
                                                       cnts + 1, odeg_sp,
                                                       nE, nbuk);
        odeg_cast_kernel<<<nbuk, 256, 0, stream>>>(partS, gcurS, odeg_sp,
                                                   u_f, v_f, tbl, nN, nU);
        agg_fused_kernel<<<nbuk, 512, 0, stream>>>(tbl, partD, gcurD,
                                                   ovfD, cnts + 1, out, nN);
    } else {
        // ---- fallback: round-5 layout ----
        int*  f_ideg = (int*)d_ws;
        int*  f_odeg = f_ideg + nN;
        int*  f_cnts = f_odeg + nN;          // [0] = ovf2_cnt
        int2* f_ovf2 = (int2*)(f_cnts + 8);
        int*  f_slack = (int*)(f_ovf2 + OVF2_CAP);

        hipMemsetAsync(d_ws, 0, ((size_t)2 * nN + 8) * sizeof(int), stream);
        long nT = ((long)nE + 3) / 4;
        build_kernel<<<(int)((nT + 255) / 256), 256, 0, stream>>>(
            src, dst, f_ideg, f_odeg, f_slack, f_ovf2, f_cnts + 0, nE);
        aggregate_f32_kernel<<<(nN + 3) / 4, 256, 0, stream>>>(
            u_f, v_f, f_slack, f_ideg, f_odeg, f_ovf2, f_cnts + 0, out, nN, nU);
    }
}